// Round 9
// baseline (198.033 us; speedup 1.0000x reference)
//
#include <hip/hip_runtime.h>
#include <hip/hip_bf16.h>
#include <math.h>

// GPT-OSS MoE: repack mxfp4 -> gate top4 -> MLP1 (MFMA) -> swiglu -> MLP2 (MFMA) -> combine
// E=32, H=1024, I=1024, N=1024 tokens, top-4.

#define NE 32
#define HD 1024
#define ID 1024
#define NTOK 1024
#define R1 2048

typedef __attribute__((ext_vector_type(8)))  short bf16x8;
typedef __attribute__((ext_vector_type(16))) float f32x16;

// ---- workspace layout (bytes) ----
#define WP1_OFF  0            // packed w1 [32][16][2048][32B] = 32 MB
#define YB_OFF   0            // yb [4096][1024] bf16 = 8 MB (aliases wp1; wp1 dead after mlp1)
#define WP2_OFF  33554432     // packed w2 [32][16][1024][32B] = 16 MB
#define SCT1_OFF 50331648     // sct1 [32][16][2048] u16 = 2 MB
#define SCT2_OFF 52428800     // sct2 [32][16][1024] u16 = 1 MB
#define TK_OFF   53477376     // t_k [16][1024][64] bf16 = 2 MB
#define AK_OFF   55574528     // a_k [16][4096][64] bf16 = 8 MB
#define CNT_OFF  63963136
#define OFFS_OFF 63963392
#define TOKL_OFF 63963648     // int[32*1024]
#define TIDX_OFF 64094720
#define TWT_OFF  64111104
#define POS_OFF  64127488

__device__ __forceinline__ unsigned f2bf(float f) {
    unsigned u = __float_as_uint(f);
    return (u + 0x7FFFu + ((u >> 16) & 1u)) >> 16;   // RNE
}
__device__ __forceinline__ float bf2f(unsigned u) {
    return __uint_as_float(u << 16);
}

// decode 8 packed fp4 (u32 = 8 nibbles) -> bf16x8, scale folded as packed exp add.
__device__ __forceinline__ bf16x8 dec8p(unsigned packed, unsigned dd) {
    unsigned selE = packed & 0x07070707u;
    unsigned sE   = packed & 0x08080808u;
    unsigned ph   = packed >> 4;
    unsigned selO = ph & 0x07070707u;
    unsigned sO   = ph & 0x08080808u;
    const unsigned PH_hi = 0x40404040u, PH_lo = 0x3F3F3F14u;
    const unsigned PL_hi = 0xC0804000u, PL_lo = 0xC0800000u;
    unsigned hbE = __builtin_amdgcn_perm(PH_hi, PH_lo, selE) | (sE << 4);
    unsigned lbE = __builtin_amdgcn_perm(PL_hi, PL_lo, selE);
    unsigned hbO = __builtin_amdgcn_perm(PH_hi, PH_lo, selO) | (sO << 4);
    unsigned lbO = __builtin_amdgcn_perm(PL_hi, PL_lo, selO);
    unsigned mE0 = __builtin_amdgcn_perm(hbE, lbE, 0x05010400u);
    unsigned mE1 = __builtin_amdgcn_perm(hbE, lbE, 0x07030602u);
    unsigned mO0 = __builtin_amdgcn_perm(hbO, lbO, 0x05010400u);
    unsigned mO1 = __builtin_amdgcn_perm(hbO, lbO, 0x07030602u);
    unsigned r0 = __builtin_amdgcn_perm(mO0, mE0, 0x05040100u);
    unsigned r1 = __builtin_amdgcn_perm(mO0, mE0, 0x07060302u);
    unsigned r2 = __builtin_amdgcn_perm(mO1, mE1, 0x05040100u);
    unsigned r3 = __builtin_amdgcn_perm(mO1, mE1, 0x07060302u);
    unsigned o0, o1, o2, o3;
    asm("v_pk_add_u16 %0, %1, %2" : "=v"(o0) : "v"(r0), "v"(dd));
    asm("v_pk_add_u16 %0, %1, %2" : "=v"(o1) : "v"(r1), "v"(dd));
    asm("v_pk_add_u16 %0, %1, %2" : "=v"(o2) : "v"(r2), "v"(dd));
    asm("v_pk_add_u16 %0, %1, %2" : "=v"(o3) : "v"(r3), "v"(dd));
    uint4 o; o.x = o0; o.y = o1; o.z = o2; o.w = o3;
    union { uint4 u4; bf16x8 b; } cv; cv.u4 = o;
    return cv.b;
}

__device__ __forceinline__ void gll16(const void* g, void* l) {
    __builtin_amdgcn_global_load_lds(
        (const __attribute__((address_space(1))) unsigned int*)g,
        (__attribute__((address_space(3))) unsigned int*)l, 16, 0, 0);
}

#define SB __builtin_amdgcn_sched_barrier(0)
#define BAR_READDONE { asm volatile("s_waitcnt lgkmcnt(0)" ::: "memory"); SB; \
                       __builtin_amdgcn_s_barrier(); SB; }

// ---- repack: boxed int32 fp4 -> packed nibbles, k-major planes, bank-swizzled ----
// wp[e][kt][row][32B]; within a row's 8 dwords, stored[p] = logical[p ^ ((row>>2)&7)].
__global__ __launch_bounds__(256) void k_repack_w(const int* __restrict__ blocks,
                                                  unsigned* __restrict__ wp, int R)
{
    int idx = blockIdx.x * 256 + threadIdx.x;     // (e*16+kt)*R + row
    int row = idx & (R - 1);
    int ekt = idx / R;
    int e = ekt >> 4, kt = ekt & 15;
    const int4* src = (const int4*)(blocks + (size_t)(e * R + row) * 512 + kt * 32);
    unsigned d[8];
    #pragma unroll
    for (int q = 0; q < 8; q++) {
        int4 v = src[q];
        unsigned u = __builtin_amdgcn_perm((unsigned)v.y, (unsigned)v.x, 0x00000400u);
        unsigned w = __builtin_amdgcn_perm((unsigned)v.w, (unsigned)v.z, 0x04000000u);
        d[q] = __builtin_amdgcn_perm(w, u, 0x07060100u);
    }
    int x = (row >> 2) & 7;
    unsigned t;
    if (x & 1) { t=d[0];d[0]=d[1];d[1]=t; t=d[2];d[2]=d[3];d[3]=t;
                 t=d[4];d[4]=d[5];d[5]=t; t=d[6];d[6]=d[7];d[7]=t; }
    if (x & 2) { t=d[0];d[0]=d[2];d[2]=t; t=d[1];d[1]=d[3];d[3]=t;
                 t=d[4];d[4]=d[6];d[6]=t; t=d[5];d[5]=d[7];d[7]=t; }
    if (x & 4) { t=d[0];d[0]=d[4];d[4]=t; t=d[1];d[1]=d[5];d[5]=t;
                 t=d[2];d[2]=d[6];d[6]=t; t=d[3];d[3]=d[7];d[7]=t; }
    uint4 o0; o0.x=d[0]; o0.y=d[1]; o0.z=d[2]; o0.w=d[3];
    uint4 o1; o1.x=d[4]; o1.y=d[5]; o1.z=d[6]; o1.w=d[7];
    *(uint4*)(wp + (size_t)idx * 8) = o0;
    *(uint4*)(wp + (size_t)idx * 8 + 4) = o1;
}

// sct[e][kt][row] u16 = scale(g=2kt) | scale(g=2kt+1)<<8
__global__ __launch_bounds__(256) void k_repack_sc(const int* __restrict__ scales,
                                                   ushort* __restrict__ sct, int R)
{
    int idx = blockIdx.x * 256 + threadIdx.x;     // e*R + row
    int e = idx / R, row = idx & (R - 1);
    const int* src = scales + (size_t)idx * 32;
    #pragma unroll
    for (int kt = 0; kt < 16; kt++) {
        int s0 = src[2 * kt], s1 = src[2 * kt + 1];
        sct[(size_t)(e * 16 + kt) * R + row] = (ushort)((s0 & 0xFF) | ((s1 & 0xFF) << 8));
    }
}

__global__ __launch_bounds__(256) void k_gate(
    const float* __restrict__ x, const float* __restrict__ norm_w,
    const float* __restrict__ gate_w, const float* __restrict__ gate_b,
    ushort* __restrict__ t_k, int* __restrict__ top_idx, float* __restrict__ top_wt,
    int* __restrict__ counts, int* __restrict__ tok_list, int* __restrict__ pos_of)
{
    int n = blockIdx.x;
    int tid = threadIdx.x;
    __shared__ float tl[HD];
    __shared__ float red[4];
    __shared__ float logits[NE];

    const float4* xv = (const float4*)(x + (size_t)n * HD);
    float4 v = xv[tid];
    float ss = v.x * v.x + v.y * v.y + v.z * v.z + v.w * v.w;
    #pragma unroll
    for (int off = 32; off; off >>= 1) ss += __shfl_down(ss, off);
    if ((tid & 63) == 0) red[tid >> 6] = ss;
    __syncthreads();
    float tot = red[0] + red[1] + red[2] + red[3];
    float rms = rsqrtf(tot * (1.0f / HD) + 1e-5f);

    float4 w = ((const float4*)norm_w)[tid];
    float4 tv;
    tv.x = v.x * rms * w.x; tv.y = v.y * rms * w.y;
    tv.z = v.z * rms * w.z; tv.w = v.w * rms * w.w;
    ushort4 tb;
    tb.x = (ushort)f2bf(tv.x); tb.y = (ushort)f2bf(tv.y);
    tb.z = (ushort)f2bf(tv.z); tb.w = (ushort)f2bf(tv.w);
    // k-major: t_k[kt][n][64]
    *(ushort4*)&t_k[((size_t)(tid >> 4) * NTOK + n) * 64 + (tid & 15) * 4] = tb;
    ((float4*)tl)[tid] = tv;
    __syncthreads();

    int wv = tid >> 6, lane = tid & 63;
    for (int j = 0; j < 8; j++) {
        int e = wv * 8 + j;
        const float* gw = gate_w + (size_t)e * HD;
        float p = 0.f;
        #pragma unroll
        for (int q = 0; q < 16; q++) { int kk = lane + q * 64; p += tl[kk] * gw[kk]; }
        #pragma unroll
        for (int off = 32; off; off >>= 1) p += __shfl_down(p, off);
        if (lane == 0) logits[e] = p + gate_b[e];
    }
    __syncthreads();

    if (tid == 0) {
        float vals[4]; int idx[4];
        unsigned used = 0;
        #pragma unroll
        for (int kk = 0; kk < 4; kk++) {
            float best = -1e30f; int bi = 0;
            for (int e2 = 0; e2 < NE; e2++) {
                if (used & (1u << e2)) continue;
                if (logits[e2] > best) { best = logits[e2]; bi = e2; }
            }
            used |= 1u << bi; vals[kk] = best; idx[kk] = bi;
        }
        float m = vals[0], s = 0.f, ex[4];
        #pragma unroll
        for (int kk = 0; kk < 4; kk++) { ex[kk] = __expf(vals[kk] - m); s += ex[kk]; }
        float inv = 1.0f / s;
        #pragma unroll
        for (int kk = 0; kk < 4; kk++) {
            top_idx[n * 4 + kk] = idx[kk];
            top_wt[n * 4 + kk] = ex[kk] * inv;
            int slot = atomicAdd(counts + idx[kk], 1);
            tok_list[idx[kk] * NTOK + slot] = n;
            pos_of[n * 4 + kk] = slot;
        }
    }
}

__global__ void k_prefix(const int* __restrict__ counts, int* __restrict__ offsets)
{
    if (threadIdx.x == 0) {
        int s = 0;
        for (int e = 0; e < NE; e++) { offsets[e] = s; s += counts[e]; }
        offsets[NE] = s;
    }
}

// ---- MLP pipeline macros. per tile per wave: 1 wgll + 4 tgll + 2 scale u16 = 7 vmem ops ----
#define MLP_ISSUE(buf, kt, S0, S1)                                           \
    {                                                                        \
        gll16(pwW + (size_t)(kt) * WSTEP, &wlds[buf][wu << 10]);             \
        _Pragma("unroll")                                                    \
        for (int i_ = 0; i_ < 4; i_++)                                       \
            gll16(tpp[i_] + (size_t)(kt) * TSTEP,                            \
                  &tlds[buf][((wu << 2) + i_) << 10]);                       \
        S0 = (int)spA[(size_t)(kt) * RSC];                                   \
        S1 = (int)spB[(size_t)(kt) * RSC];                                   \
    }

#define MLP_COMPUTE(buf, S0, S1)                                             \
    _Pragma("unroll")                                                        \
    for (int ks = 0; ks < 4; ks++) {                                         \
        int s0_ = ks < 2 ? (S0 & 0xFF) : (S0 >> 8);                          \
        int s1_ = ks < 2 ? (S1 & 0xFF) : (S1 >> 8);                          \
        unsigned d0_ = (unsigned)((s0_ - 127) << 7) & 0xFFFFu;               \
        unsigned d1_ = (unsigned)((s1_ - 127) << 7) & 0xFFFFu;               \
        d0_ |= d0_ << 16; d1_ |= d1_ << 16;                                  \
        int s_ = ks * 2 + kh;                                                \
        unsigned w0_ = *(const unsigned*)&wlds[buf][(rl0 * 8 + (s_ ^ wsw)) * 4]; \
        unsigned w1_ = *(const unsigned*)&wlds[buf][(rl1 * 8 + (s_ ^ wsw)) * 4]; \
        bf16x8 wf0 = dec8p(w0_, d0_);                                        \
        bf16x8 wf1 = dec8p(w1_, d1_);                                        \
        _Pragma("unroll")                                                    \
        for (int mt = 0; mt < 2; mt++) {                                     \
            if (act[mt]) {                                                   \
                bf16x8 af = *(const bf16x8*)&tlds[buf][(((wt * 2 + mt) * 32 + lr) << 7) + ((s_ ^ (lr & 7)) << 4)]; \
                acc[0][mt] = __builtin_amdgcn_mfma_f32_32x32x16_bf16(af, wf0, acc[0][mt], 0, 0, 0); \
                acc[1][mt] = __builtin_amdgcn_mfma_f32_32x32x16_bf16(af, wf1, acc[1][mt], 0, 0, 0); \
            }                                                                \
        }                                                                    \
    }

#define MLP_KLOOP                                                            \
    MLP_ISSUE(0, 0, scA0, scA1);                                             \
    MLP_ISSUE(1, 1, scB0, scB1);                                             \
    SB;                                                                      \
    asm volatile("s_waitcnt vmcnt(7)" ::: "memory"); SB;                     \
    __builtin_amdgcn_s_barrier(); SB;                                        \
    _Pragma("unroll 1")                                                      \
    for (int kt2 = 0; kt2 < 16; kt2 += 2) {                                  \
        MLP_COMPUTE(0, scA0, scA1);                                          \
        BAR_READDONE;                                                        \
        if (kt2 < 14) {                                                      \
            MLP_ISSUE(0, kt2 + 2, scA0, scA1); SB;                           \
            asm volatile("s_waitcnt vmcnt(7)" ::: "memory");                 \
        } else {                                                             \
            asm volatile("s_waitcnt vmcnt(0)" ::: "memory");                 \
        }                                                                    \
        SB; __builtin_amdgcn_s_barrier(); SB;                                \
        MLP_COMPUTE(1, scB0, scB1);                                          \
        BAR_READDONE;                                                        \
        if (kt2 < 14) {                                                      \
            MLP_ISSUE(1, kt2 + 3, scB0, scB1); SB;                           \
            asm volatile("s_waitcnt vmcnt(7)" ::: "memory");                 \
            SB; __builtin_amdgcn_s_barrier(); SB;                            \
        }                                                                    \
    }

// MLP1 + swiglu. Block: expert x 128 rows x 128-token chunk (z-split). Waves 2x2.
__global__ __launch_bounds__(256, 3) void k_mlp1(
    const ushort* __restrict__ t_k, const unsigned* __restrict__ wp,
    const ushort* __restrict__ sct, const float* __restrict__ bias,
    const int* __restrict__ counts, const int* __restrict__ offsets,
    const int* __restrict__ tok_list, ushort* __restrict__ a_k)
{
    const int WSTEP = R1 * 32;            // bytes per kt plane (weights)
    const int TSTEP = NTOK * 128;         // bytes per kt plane (tokens)
    const int RSC = R1;
    int e = blockIdx.y;
    int cnt = counts[e];
    if (cnt == 0) return;
    int r0 = blockIdx.x * 128;
    int tid = threadIdx.x;
    int l = tid & 63;
    int lr = l & 31, kh = l >> 5;
    int wu = __builtin_amdgcn_readfirstlane(tid >> 6);
    int wr = wu >> 1, wt = wu & 1;
    int base = offsets[e];

    __shared__ char tlds[2][16384];       // tokens [128 tok][128B], slot-swizzled by tok&7
    __shared__ char wlds[2][4096];        // packed weights [128 rows][32B], dword-swizzled

    int wsw = (lr >> 2) & 7;
    int rl0 = wr * 64 + lr, rl1 = rl0 + 32;
    int rowA = r0 + rl0, rowB = r0 + rl1;
    const ushort* spA = sct + (size_t)e * 16 * R1 + rowA;
    const ushort* spB = spA + 32;
    float blA = bias[e * R1 + rowA];
    float blB = bias[e * R1 + rowB];
    asm volatile("" :: "v"(blA), "v"(blB));

    const char* pwW = (const char*)wp + (size_t)e * 16 * R1 * 32 + (size_t)r0 * 32
                      + (wu << 10) + (l << 4);
    int blk = ((l & 7) ^ ((l >> 3) & 7)) << 4;
    int g0 = r0 >> 7;                     // a_k output plane

    for (int c0 = blockIdx.z * 128; c0 < cnt; c0 += 256) {
        int nt = min(128, cnt - c0);
        bool act[2] = { (wt * 2) * 32 < nt, (wt * 2 + 1) * 32 < nt };
        const char* tpp[4];
        #pragma unroll
        for (int i = 0; i < 4; i++) {
            int t = wu * 32 + i * 8 + (l >> 3);
            int tc = t < nt ? t : nt - 1;
            int n = tok_list[e * NTOK + c0 + tc];
            tpp[i] = (const char*)t_k + (size_t)n * 128 + blk;
        }
        asm volatile("s_waitcnt vmcnt(0)" ::: "memory"); SB;

        int scA0, scA1, scB0, scB1;
        f32x16 acc[2][2] = {};

        MLP_KLOOP;

        // epilogue: bias + swiglu (glu/lin = adjacent lanes = adjacent rows) -> a_k
        #pragma unroll
        for (int nn = 0; nn < 2; nn++) {
            float bl = nn ? blB : blA;
            int row = nn ? rowB : rowA;
            int cc = (row >> 1) & 63;
            #pragma unroll
            for (int mt = 0; mt < 2; mt++) {
                if (act[mt]) {
                    #pragma unroll
                    for (int r = 0; r < 16; r++) {
                        float hv = acc[nn][mt][r] + bl;
                        float other = __shfl_xor(hv, 1, 64);
                        int m = (r & 3) + 8 * (r >> 2) + 4 * kh;
                        int tokg = c0 + (wt * 2 + mt) * 32 + m;
                        if (!(l & 1) && tokg < cnt) {
                            float hg = fminf(hv, 7.0f);
                            float hx = fminf(fmaxf(other, -7.0f), 7.0f);
                            float sig = 1.0f / (1.0f + __expf(-1.702f * hg));
                            float av = hg * sig * (hx + 1.0f);
                            a_k[(size_t)g0 * 262144 + (size_t)(base + tokg) * 64 + cc]
                                = (ushort)f2bf(av);
                        }
                    }
                }
            }
        }
    }
}

// MLP2. Token source = a_k planes (contiguous slots). Writes yb[slot][h].
__global__ __launch_bounds__(256, 3) void k_mlp2(
    const ushort* __restrict__ a_k, const unsigned* __restrict__ wp,
    const ushort* __restrict__ sct, const float* __restrict__ bias,
    const int* __restrict__ counts, const int* __restrict__ offsets,
    ushort* __restrict__ yb)
{
    const int WSTEP = HD * 32;
    const int TSTEP = 4096 * 128;
    const int RSC = HD;
    int e = blockIdx.y;
    int cnt = counts[e];
    if (cnt == 0) return;
    int r0 = blockIdx.x * 128;
    int tid = threadIdx.x;
    int l = tid & 63;
    int lr = l & 31, kh = l >> 5;
    int wu = __builtin_amdgcn_readfirstlane(tid >> 6);
    int wr = wu >> 1, wt = wu & 1;
    int base = offsets[e];

    __shared__ char tlds[2][16384];
    __shared__ char wlds[2][4096];

    int wsw = (lr >> 2) & 7;
    int rl0 = wr * 64 + lr, rl1 = rl0 + 32;
    int rowA = r0 + rl0, rowB = r0 + rl1;
    const ushort* spA = sct + (size_t)e * 16 * HD + rowA;
    const ushort* spB = spA + 32;
    float blA = bias[e * HD + rowA];
    float blB = bias[e * HD + rowB];
    asm volatile("" :: "v"(blA), "v"(blB));

    const char* pwW = (const char*)wp + (size_t)e * 16 * HD * 32 + (size_t)r0 * 32
                      + (wu << 10) + (l << 4);
    int blk = ((l & 7) ^ ((l >> 3) & 7)) << 4;

    for (int c0 = blockIdx.z * 128; c0 < cnt; c0 += 256) {
        int nt = min(128, cnt - c0);
        bool act[2] = { (wt * 2) * 32 < nt, (wt * 2 + 1) * 32 < nt };
        const char* tpp[4];
        #pragma unroll
        for (int i = 0; i < 4; i++) {
            int t = wu * 32 + i * 8 + (l >> 3);
            int tc = t < nt ? t : nt - 1;
            tpp[i] = (const char*)a_k + (size_t)(base + c0 + tc) * 128 + blk;
        }
        asm volatile("s_waitcnt vmcnt(0)" ::: "memory"); SB;

        int scA0, scA1, scB0, scB1;
        f32x16 acc[2][2] = {};

        MLP_KLOOP;

        #pragma unroll
        for (int nn = 0; nn < 2; nn++) {
            float bl = nn ? blB : blA;
            int row = nn ? rowB : rowA;
            #pragma unroll
            for (int mt = 0; mt < 2; mt++) {
                if (act[mt]) {
                    #pragma unroll
                    for (int r = 0; r < 16; r++) {
                        int m = (r & 3) + 8 * (r >> 2) + 4 * kh;
                        int tokg = c0 + (wt * 2 + mt) * 32 + m;
                        if (tokg < cnt) {
                            float y = acc[nn][mt][r] + bl;
                            yb[(size_t)(base + tokg) * HD + row] = (ushort)f2bf(y);
                        }
                    }
                }
            }
        }
    }
}

__global__ __launch_bounds__(256) void k_combine(
    const float* __restrict__ x, const ushort* __restrict__ yb,
    const int* __restrict__ top_idx, const float* __restrict__ top_wt,
    const int* __restrict__ pos_of, const int* __restrict__ offsets,
    float* __restrict__ out)
{
    int n = blockIdx.x, tid = threadIdx.x;
    float4 xv = ((const float4*)(x + (size_t)n * HD))[tid];
    float r0 = xv.x, r1 = xv.y, r2 = xv.z, r3 = xv.w;
    #pragma unroll
    for (int k = 0; k < 4; k++) {
        int e = top_idx[n * 4 + k];
        float wt = top_wt[n * 4 + k];
        int slot = offsets[e] + pos_of[n * 4 + k];
        ushort4 yv = ((const ushort4*)(yb + (size_t)slot * HD))[tid];
        r0 += wt * bf2f(yv.x); r1 += wt * bf2f(yv.y);
        r2 += wt * bf2f(yv.z); r3 += wt * bf2f(yv.w);
    }
    float4 ov; ov.x = r0; ov.y = r1; ov.z = r2; ov.w = r3;
    ((float4*)(out + (size_t)n * HD))[tid] = ov;
}

extern "C" void kernel_launch(void* const* d_in, const int* in_sizes, int n_in,
                              void* d_out, int out_size, void* d_ws, size_t ws_size,
                              hipStream_t stream)
{
    const float* x           = (const float*)d_in[0];
    const float* norm_w      = (const float*)d_in[1];
    const float* gate_w      = (const float*)d_in[2];
    const float* gate_b      = (const float*)d_in[3];
    const float* mlp1_bias   = (const float*)d_in[4];
    const float* mlp2_bias   = (const float*)d_in[5];
    const int*   mlp1_blocks = (const int*)d_in[6];
    const int*   mlp1_scales = (const int*)d_in[7];
    const int*   mlp2_blocks = (const int*)d_in[8];
    const int*   mlp2_scales = (const int*)d_in[9];
    float* out = (float*)d_out;

    char* ws = (char*)d_ws;
    unsigned* wp1   = (unsigned*)(ws + WP1_OFF);
    unsigned* wp2   = (unsigned*)(ws + WP2_OFF);
    ushort* sct1    = (ushort*)(ws + SCT1_OFF);
    ushort* sct2    = (ushort*)(ws + SCT2_OFF);
    ushort* t_k     = (ushort*)(ws + TK_OFF);
    ushort* a_k     = (ushort*)(ws + AK_OFF);
    ushort* yb      = (ushort*)(ws + YB_OFF);      // aliases wp1 (dead after mlp1)
    int*   counts   = (int*)(ws + CNT_OFF);
    int*   offsets  = (int*)(ws + OFFS_OFF);
    int*   tok_list = (int*)(ws + TOKL_OFF);
    int*   top_idx  = (int*)(ws + TIDX_OFF);
    float* top_wt   = (float*)(ws + TWT_OFF);
    int*   pos_of   = (int*)(ws + POS_OFF);

    hipMemsetAsync(counts, 0, NE * sizeof(int), stream);
    k_repack_w<<<NE * R1 * 16 / 256, 256, 0, stream>>>(mlp1_blocks, wp1, R1);
    k_repack_w<<<NE * HD * 16 / 256, 256, 0, stream>>>(mlp2_blocks, wp2, HD);
    k_repack_sc<<<NE * R1 / 256, 256, 0, stream>>>(mlp1_scales, sct1, R1);
    k_repack_sc<<<NE * HD / 256, 256, 0, stream>>>(mlp2_scales, sct2, HD);
    k_gate<<<NTOK, 256, 0, stream>>>(x, norm_w, gate_w, gate_b, t_k, top_idx, top_wt,
                                     counts, tok_list, pos_of);
    k_prefix<<<1, 64, 0, stream>>>(counts, offsets);
    k_mlp1<<<dim3(16, NE, 2), 256, 0, stream>>>(t_k, wp1, sct1, mlp1_bias,
                                                counts, offsets, tok_list, a_k);
    k_mlp2<<<dim3(8, NE, 2), 256, 0, stream>>>(a_k, wp2, sct2, mlp2_bias,
                                               counts, offsets, yb);
    k_combine<<<NTOK, 256, 0, stream>>>(x, yb, top_idx, top_wt, pos_of, offsets, out);
}

// Round 10
// 178.448 us; speedup vs baseline: 1.1098x; 1.1098x over previous
//
#include <hip/hip_runtime.h>
#include <hip/hip_bf16.h>
#include <math.h>

// GPT-OSS MoE: repack mxfp4 -> gate top4 -> MLP1 (MFMA) -> swiglu -> MLP2 (MFMA) -> combine
// E=32, H=1024, I=1024, N=1024 tokens, top-4. Barrier-free wave-private MLP pipeline.

#define NE 32
#define HD 1024
#define ID 1024
#define NTOK 1024
#define R1 2048
#define SLOTS 32768              // 32 experts x 1024 padded slots
#define TSTEP 4194304            // bytes per kt plane of t_s / a_k (SLOTS*128)

typedef __attribute__((ext_vector_type(8)))  short bf16x8;
typedef __attribute__((ext_vector_type(16))) float f32x16;

// ---- workspace layout (bytes) ----
#define WP1_OFF  0               // packed w1 [32][16][2048][32B] = 32 MB
#define WP2_OFF  33554432        // packed w2 [32][16][1024][32B] = 16 MB
#define SCT1_OFF 50331648        // sct1 [32][2048][16] u16 = 2 MB
#define SCT2_OFF 52428800        // sct2 [32][1024][16] u16 = 1 MB
#define TS_OFF   53477376        // t_s [16][32768][64] bf16 = 64 MB
#define AK_OFF   120586240       // a_k [16][32768][64] bf16 = 64 MB
#define YB_OFF   187695104       // yb  [32768][1024] bf16 = 64 MB
#define CNT_OFF  254803968
#define TIDX_OFF 254804224
#define TWT_OFF  254820608
#define POS_OFF  254836992

__device__ __forceinline__ unsigned f2bf(float f) {
    unsigned u = __float_as_uint(f);
    return (u + 0x7FFFu + ((u >> 16) & 1u)) >> 16;   // RNE
}
__device__ __forceinline__ float bf2f(unsigned u) {
    return __uint_as_float(u << 16);
}

// decode 8 packed fp4 (u32 = 8 nibbles) -> bf16x8, scale folded as packed exp add.
__device__ __forceinline__ bf16x8 dec8p(unsigned packed, unsigned dd) {
    unsigned selE = packed & 0x07070707u;
    unsigned sE   = packed & 0x08080808u;
    unsigned ph   = packed >> 4;
    unsigned selO = ph & 0x07070707u;
    unsigned sO   = ph & 0x08080808u;
    const unsigned PH_hi = 0x40404040u, PH_lo = 0x3F3F3F14u;
    const unsigned PL_hi = 0xC0804000u, PL_lo = 0xC0800000u;
    unsigned hbE = __builtin_amdgcn_perm(PH_hi, PH_lo, selE) | (sE << 4);
    unsigned lbE = __builtin_amdgcn_perm(PL_hi, PL_lo, selE);
    unsigned hbO = __builtin_amdgcn_perm(PH_hi, PH_lo, selO) | (sO << 4);
    unsigned lbO = __builtin_amdgcn_perm(PL_hi, PL_lo, selO);
    unsigned mE0 = __builtin_amdgcn_perm(hbE, lbE, 0x05010400u);
    unsigned mE1 = __builtin_amdgcn_perm(hbE, lbE, 0x07030602u);
    unsigned mO0 = __builtin_amdgcn_perm(hbO, lbO, 0x05010400u);
    unsigned mO1 = __builtin_amdgcn_perm(hbO, lbO, 0x07030602u);
    unsigned r0 = __builtin_amdgcn_perm(mO0, mE0, 0x05040100u);
    unsigned r1 = __builtin_amdgcn_perm(mO0, mE0, 0x07060302u);
    unsigned r2 = __builtin_amdgcn_perm(mO1, mE1, 0x05040100u);
    unsigned r3 = __builtin_amdgcn_perm(mO1, mE1, 0x07060302u);
    unsigned o0, o1, o2, o3;
    asm("v_pk_add_u16 %0, %1, %2" : "=v"(o0) : "v"(r0), "v"(dd));
    asm("v_pk_add_u16 %0, %1, %2" : "=v"(o1) : "v"(r1), "v"(dd));
    asm("v_pk_add_u16 %0, %1, %2" : "=v"(o2) : "v"(r2), "v"(dd));
    asm("v_pk_add_u16 %0, %1, %2" : "=v"(o3) : "v"(r3), "v"(dd));
    uint4 o; o.x = o0; o.y = o1; o.z = o2; o.w = o3;
    union { uint4 u4; bf16x8 b; } cv; cv.u4 = o;
    return cv.b;
}

__device__ __forceinline__ void gll16(const void* g, void* l) {
    __builtin_amdgcn_global_load_lds(
        (const __attribute__((address_space(1))) unsigned int*)g,
        (__attribute__((address_space(3))) unsigned int*)l, 16, 0, 0);
}

#define SB __builtin_amdgcn_sched_barrier(0)

__device__ __forceinline__ unsigned sc_sel(uint4 a, uint4 b, int kt2) {
    int idx = kt2 >> 1;
    unsigned r0_ = (idx & 4) ? b.x : a.x;
    unsigned r1_ = (idx & 4) ? b.y : a.y;
    unsigned r2_ = (idx & 4) ? b.z : a.z;
    unsigned r3_ = (idx & 4) ? b.w : a.w;
    unsigned lo = (idx & 1) ? r1_ : r0_;
    unsigned hi = (idx & 1) ? r3_ : r2_;
    return (idx & 2) ? hi : lo;
}

// ---- merged repack: boxed fp4 -> packed k-major planes (bank-swizzle baked) + scales ----
__device__ __forceinline__ void repack_w_item(const int* __restrict__ blocks,
                                              unsigned* __restrict__ wp, int rsh, int idx)
{
    int R = 1 << rsh;
    int row = idx & (R - 1);
    int ekt = idx >> rsh;                         // e*16 + kt
    const int4* src = (const int4*)(blocks + ((size_t)(ekt >> 4) * R + row) * 512
                                    + (ekt & 15) * 32);
    unsigned d[8];
    #pragma unroll
    for (int q = 0; q < 8; q++) {
        int4 v = src[q];
        unsigned u = __builtin_amdgcn_perm((unsigned)v.y, (unsigned)v.x, 0x00000400u);
        unsigned w = __builtin_amdgcn_perm((unsigned)v.w, (unsigned)v.z, 0x04000000u);
        d[q] = __builtin_amdgcn_perm(w, u, 0x07060100u);
    }
    int r63 = row & 63;
    int x = (r63 ^ (r63 >> 3)) & 7;               // stored[d] = logical[d ^ x]
    unsigned t;
    if (x & 1) { t=d[0];d[0]=d[1];d[1]=t; t=d[2];d[2]=d[3];d[3]=t;
                 t=d[4];d[4]=d[5];d[5]=t; t=d[6];d[6]=d[7];d[7]=t; }
    if (x & 2) { t=d[0];d[0]=d[2];d[2]=t; t=d[1];d[1]=d[3];d[3]=t;
                 t=d[4];d[4]=d[6];d[6]=t; t=d[5];d[5]=d[7];d[7]=t; }
    if (x & 4) { t=d[0];d[0]=d[4];d[4]=t; t=d[1];d[1]=d[5];d[5]=t;
                 t=d[2];d[2]=d[6];d[6]=t; t=d[3];d[3]=d[7];d[7]=t; }
    uint4 o0; o0.x=d[0]; o0.y=d[1]; o0.z=d[2]; o0.w=d[3];
    uint4 o1; o1.x=d[4]; o1.y=d[5]; o1.z=d[6]; o1.w=d[7];
    *(uint4*)(wp + (size_t)idx * 8) = o0;
    *(uint4*)(wp + (size_t)idx * 8 + 4) = o1;
}

__device__ __forceinline__ void repack_sc_item(const int* __restrict__ scales,
                                               ushort* __restrict__ sct, int idx)
{
    const int* src = scales + (size_t)idx * 32;   // idx = e*R + row
    unsigned o[8];
    #pragma unroll
    for (int d = 0; d < 8; d++) {
        unsigned w0 = (src[4*d] & 0xFF) | ((src[4*d+1] & 0xFF) << 8);
        unsigned w1 = (src[4*d+2] & 0xFF) | ((src[4*d+3] & 0xFF) << 8);
        o[d] = w0 | (w1 << 16);
    }
    uint4 a; a.x=o[0]; a.y=o[1]; a.z=o[2]; a.w=o[3];
    uint4 b; b.x=o[4]; b.y=o[5]; b.z=o[6]; b.w=o[7];
    *(uint4*)(sct + (size_t)idx * 16) = a;
    *(uint4*)(sct + (size_t)idx * 16 + 8) = b;
}

__global__ __launch_bounds__(256) void k_repack(
    const int* __restrict__ b1, const int* __restrict__ b2,
    const int* __restrict__ s1, const int* __restrict__ s2,
    unsigned* __restrict__ wp1, unsigned* __restrict__ wp2,
    ushort* __restrict__ sct1, ushort* __restrict__ sct2)
{
    int b = blockIdx.x, tid = threadIdx.x;
    if (b < 4096)       repack_w_item(b1, wp1, 11, b * 256 + tid);
    else if (b < 6144)  repack_w_item(b2, wp2, 10, (b - 4096) * 256 + tid);
    else if (b < 6400)  repack_sc_item(s1, sct1, (b - 6144) * 256 + tid);
    else                repack_sc_item(s2, sct2, (b - 6400) * 256 + tid);
}

__global__ __launch_bounds__(256) void k_gate(
    const float* __restrict__ x, const float* __restrict__ norm_w,
    const float* __restrict__ gate_w, const float* __restrict__ gate_b,
    ushort* __restrict__ t_s, int* __restrict__ top_idx, float* __restrict__ top_wt,
    int* __restrict__ counts, int* __restrict__ pos_of)
{
    int n = blockIdx.x;
    int tid = threadIdx.x;
    __shared__ float tl[HD];
    __shared__ float red[4];
    __shared__ float logits[NE];
    __shared__ int s_se[4], s_sl[4];

    const float4* xv = (const float4*)(x + (size_t)n * HD);
    float4 v = xv[tid];
    float ss = v.x * v.x + v.y * v.y + v.z * v.z + v.w * v.w;
    #pragma unroll
    for (int off = 32; off; off >>= 1) ss += __shfl_down(ss, off);
    if ((tid & 63) == 0) red[tid >> 6] = ss;
    __syncthreads();
    float tot = red[0] + red[1] + red[2] + red[3];
    float rms = rsqrtf(tot * (1.0f / HD) + 1e-5f);

    float4 w = ((const float4*)norm_w)[tid];
    float4 tv;
    tv.x = v.x * rms * w.x; tv.y = v.y * rms * w.y;
    tv.z = v.z * rms * w.z; tv.w = v.w * rms * w.w;
    ushort4 tb;
    tb.x = (ushort)f2bf(tv.x); tb.y = (ushort)f2bf(tv.y);
    tb.z = (ushort)f2bf(tv.z); tb.w = (ushort)f2bf(tv.w);
    ((float4*)tl)[tid] = tv;
    __syncthreads();

    int wv = tid >> 6, lane = tid & 63;
    for (int j = 0; j < 8; j++) {
        int e = wv * 8 + j;
        const float* gw = gate_w + (size_t)e * HD;
        float p = 0.f;
        #pragma unroll
        for (int q = 0; q < 16; q++) { int kk = lane + q * 64; p += tl[kk] * gw[kk]; }
        #pragma unroll
        for (int off = 32; off; off >>= 1) p += __shfl_down(p, off);
        if (lane == 0) logits[e] = p + gate_b[e];
    }
    __syncthreads();

    if (tid == 0) {
        float vals[4]; int idx[4];
        unsigned used = 0;
        #pragma unroll
        for (int kk = 0; kk < 4; kk++) {
            float best = -1e30f; int bi = 0;
            for (int e2 = 0; e2 < NE; e2++) {
                if (used & (1u << e2)) continue;
                if (logits[e2] > best) { best = logits[e2]; bi = e2; }
            }
            used |= 1u << bi; vals[kk] = best; idx[kk] = bi;
        }
        float m = vals[0], s = 0.f, ex[4];
        #pragma unroll
        for (int kk = 0; kk < 4; kk++) { ex[kk] = __expf(vals[kk] - m); s += ex[kk]; }
        float inv = 1.0f / s;
        #pragma unroll
        for (int kk = 0; kk < 4; kk++) {
            top_idx[n * 4 + kk] = idx[kk];
            top_wt[n * 4 + kk] = ex[kk] * inv;
            int slot = atomicAdd(counts + idx[kk], 1);
            pos_of[n * 4 + kk] = slot;
            s_se[kk] = idx[kk]; s_sl[kk] = slot;
        }
    }
    __syncthreads();

    // scatter this token's rmsnorm'd slice into t_s[kt][(e<<10)+slot][64]
    int kt = tid >> 4, off = (tid & 15) * 4;
    #pragma unroll
    for (int kk = 0; kk < 4; kk++) {
        int slot = (s_se[kk] << 10) + s_sl[kk];
        *(ushort4*)&t_s[((size_t)kt * SLOTS + slot) * 64 + off] = tb;
    }
}

// ================= MLP1: barrier-free, wave-private staging =================
#define M1_ISSUE(buf, kt) {                                                   \
    const char* ws_ = wsrc + (size_t)(kt) * 65536;                            \
    gll16(ws_, myw + (buf) * 2048);                                           \
    gll16(ws_ + 1024, myw + (buf) * 2048 + 1024);                             \
    const char* ts_ = tsrc + (size_t)(kt) * TSTEP;                            \
    _Pragma("unroll")                                                         \
    for (int i_ = 0; i_ < 8; i_++)                                            \
        gll16(ts_ + i_ * 1024, myt + (buf) * 8192 + i_ * 1024);               \
}

#define M1_COMPUTE(buf, wordA, wordB) {                                       \
    unsigned wa_ = (wordA), wb_ = (wordB);                                    \
    unsigned dAl = (unsigned)(((int)(wa_ & 0xFF) - 127) << 7) & 0xFFFFu; dAl |= dAl << 16; \
    unsigned dAh = (unsigned)(((int)((wa_ >> 8) & 0xFF) - 127) << 7) & 0xFFFFu; dAh |= dAh << 16; \
    unsigned dBl = (unsigned)(((int)(wb_ & 0xFF) - 127) << 7) & 0xFFFFu; dBl |= dBl << 16; \
    unsigned dBh = (unsigned)(((int)((wb_ >> 8) & 0xFF) - 127) << 7) & 0xFFFFu; dBh |= dBh << 16; \
    _Pragma("unroll")                                                         \
    for (int ks = 0; ks < 4; ks++) {                                          \
        int s_ = ks * 2 + kh;                                                 \
        unsigned w0_ = *(const unsigned*)(myw + (buf) * 2048 + lr * 32 + ((s_ ^ swz0) << 2)); \
        unsigned w1_ = *(const unsigned*)(myw + (buf) * 2048 + (32 + lr) * 32 + ((s_ ^ swz1) << 2)); \
        bf16x8 wf0 = dec8p(w0_, ks < 2 ? dAl : dAh);                          \
        bf16x8 wf1 = dec8p(w1_, ks < 2 ? dBl : dBh);                          \
        bf16x8 af0 = *(const bf16x8*)(myt + (buf) * 8192 + lr * 128 + ((s_ ^ (lr & 7)) << 4)); \
        bf16x8 af1 = *(const bf16x8*)(myt + (buf) * 8192 + (32 + lr) * 128 + ((s_ ^ (lr & 7)) << 4)); \
        a00 = __builtin_amdgcn_mfma_f32_32x32x16_bf16(af0, wf0, a00, 0, 0, 0); \
        a01 = __builtin_amdgcn_mfma_f32_32x32x16_bf16(af1, wf0, a01, 0, 0, 0); \
        a10 = __builtin_amdgcn_mfma_f32_32x32x16_bf16(af0, wf1, a10, 0, 0, 0); \
        a11 = __builtin_amdgcn_mfma_f32_32x32x16_bf16(af1, wf1, a11, 0, 0, 0); \
    }                                                                         \
}

#define M1_EPI(ac, nn, mt) {                                                  \
    float bl = (nn) ? blB : blA;                                              \
    int row_ = (nn) ? rowB : rowA;                                            \
    int cc = (row_ >> 1) & 63;                                                \
    _Pragma("unroll")                                                         \
    for (int r = 0; r < 16; r++) {                                            \
        float hv = ac[r] + bl;                                                \
        float other = __shfl_xor(hv, 1, 64);                                  \
        int m = (r & 3) + 8 * (r >> 2) + 4 * kh;                              \
        int tokg = c0 + wt * 64 + (mt) * 32 + m;                              \
        if (!(l & 1) && tokg < cnt) {                                         \
            float hg = fminf(hv, 7.0f);                                       \
            float hx = fminf(fmaxf(other, -7.0f), 7.0f);                      \
            float sig = 1.0f / (1.0f + __expf(-1.702f * hg));                 \
            float av = hg * sig * (hx + 1.0f);                                \
            a_k[((size_t)g0 * SLOTS + sbase + tokg) * 64 + cc] = (ushort)f2bf(av); \
        }                                                                     \
    }                                                                         \
}

__global__ __launch_bounds__(256, 2) void k_mlp1(
    const ushort* __restrict__ t_s, const unsigned* __restrict__ wp,
    const ushort* __restrict__ sct, const float* __restrict__ bias,
    const int* __restrict__ counts, ushort* __restrict__ a_k)
{
    int e = blockIdx.y;
    int cnt = counts[e];
    if (cnt == 0) return;
    int c00 = blockIdx.z * 128;
    if (c00 >= cnt) return;
    int r0 = blockIdx.x * 128;
    int tid = threadIdx.x;
    int l = tid & 63, lr = l & 31, kh = l >> 5;
    int wu = __builtin_amdgcn_readfirstlane(tid >> 6);
    int wr = wu >> 1, wt = wu & 1;
    int sbase = e << 10;
    int g0 = r0 >> 7;

    __shared__ char lds_all[81920];
    char* myt = lds_all + wu * 20480;            // tokens: 2 x 8 KB
    char* myw = myt + 16384;                     // weights: 2 x 2 KB

    int rowA = r0 + wr * 64 + lr, rowB = rowA + 32;
    float blA = bias[e * R1 + rowA];
    float blB = bias[e * R1 + rowB];
    const uint4* spA = (const uint4*)(sct + (size_t)(e * R1 + rowA) * 16);
    const uint4* spB = (const uint4*)(sct + (size_t)(e * R1 + rowB) * 16);
    uint4 sA0 = spA[0], sA1 = spA[1];
    uint4 sB0 = spB[0], sB1 = spB[1];
    unsigned pin = sA0.x ^ sA0.y ^ sA0.z ^ sA0.w ^ sA1.x ^ sA1.y ^ sA1.z ^ sA1.w
                 ^ sB0.x ^ sB0.y ^ sB0.z ^ sB0.w ^ sB1.x ^ sB1.y ^ sB1.z ^ sB1.w;
    asm volatile("" :: "v"(pin), "v"(blA), "v"(blB));   // force pre-loop retire

    const char* wsrc = (const char*)wp + (size_t)e * 16 * 65536
                       + (size_t)(r0 + wr * 64) * 32 + (l >> 1) * 32 + (l & 1) * 16;
    int tswz = ((l & 7) ^ (l >> 3)) << 4;
    int swz0 = (lr ^ (lr >> 3)) & 7;
    int swz1 = swz0 ^ 4;

    #pragma unroll 1
    for (int c0 = c00; c0 < cnt; c0 += 256) {
        const char* tsrc = (const char*)t_s
            + (size_t)(sbase + c0 + wt * 64 + (l >> 3)) * 128 + tswz;
        asm volatile("s_waitcnt vmcnt(0)" ::: "memory"); SB;

        f32x16 a00 = {}, a01 = {}, a10 = {}, a11 = {};
        M1_ISSUE(0, 0); M1_ISSUE(1, 1); SB;

        #pragma unroll 1
        for (int kt2 = 0; kt2 < 16; kt2 += 2) {
            unsigned dwA = sc_sel(sA0, sA1, kt2);
            unsigned dwB = sc_sel(sB0, sB1, kt2);
            asm volatile("s_waitcnt vmcnt(10)" ::: "memory"); SB;
            M1_COMPUTE(0, dwA & 0xFFFFu, dwB & 0xFFFFu);
            asm volatile("s_waitcnt lgkmcnt(0)" ::: "memory"); SB;
            if (kt2 < 14) { M1_ISSUE(0, kt2 + 2); SB; }
            if (kt2 < 14) { asm volatile("s_waitcnt vmcnt(10)" ::: "memory"); }
            else          { asm volatile("s_waitcnt vmcnt(0)" ::: "memory"); }
            SB;
            M1_COMPUTE(1, dwA >> 16, dwB >> 16);
            asm volatile("s_waitcnt lgkmcnt(0)" ::: "memory"); SB;
            if (kt2 < 14) { M1_ISSUE(1, kt2 + 3); SB; }
        }

        M1_EPI(a00, 0, 0); M1_EPI(a01, 0, 1);
        M1_EPI(a10, 1, 0); M1_EPI(a11, 1, 1);
    }
}

// ================= MLP2 =================
#define M2_ISSUE(buf, kt) {                                                   \
    const char* ws_ = wsrc + (size_t)(kt) * 32768;                            \
    gll16(ws_, myw + (buf) * 2048);                                           \
    gll16(ws_ + 1024, myw + (buf) * 2048 + 1024);                             \
    const char* ts_ = tsrc + (size_t)(kt) * TSTEP;                            \
    _Pragma("unroll")                                                         \
    for (int i_ = 0; i_ < 4; i_++)                                            \
        gll16(ts_ + i_ * 1024, myt + (buf) * 4096 + i_ * 1024);               \
}

#define M2_COMPUTE(buf, wordA, wordB) {                                       \
    unsigned wa_ = (wordA), wb_ = (wordB);                                    \
    unsigned dAl = (unsigned)(((int)(wa_ & 0xFF) - 127) << 7) & 0xFFFFu; dAl |= dAl << 16; \
    unsigned dAh = (unsigned)(((int)((wa_ >> 8) & 0xFF) - 127) << 7) & 0xFFFFu; dAh |= dAh << 16; \
    unsigned dBl = (unsigned)(((int)(wb_ & 0xFF) - 127) << 7) & 0xFFFFu; dBl |= dBl << 16; \
    unsigned dBh = (unsigned)(((int)((wb_ >> 8) & 0xFF) - 127) << 7) & 0xFFFFu; dBh |= dBh << 16; \
    _Pragma("unroll")                                                         \
    for (int ks = 0; ks < 4; ks++) {                                          \
        int s_ = ks * 2 + kh;                                                 \
        unsigned w0_ = *(const unsigned*)(myw + (buf) * 2048 + lr * 32 + ((s_ ^ swz0) << 2)); \
        unsigned w1_ = *(const unsigned*)(myw + (buf) * 2048 + (32 + lr) * 32 + ((s_ ^ swz1) << 2)); \
        bf16x8 wf0 = dec8p(w0_, ks < 2 ? dAl : dAh);                          \
        bf16x8 wf1 = dec8p(w1_, ks < 2 ? dBl : dBh);                          \
        bf16x8 af0 = *(const bf16x8*)(myt + (buf) * 4096 + lr * 128 + ((s_ ^ (lr & 7)) << 4)); \
        a0 = __builtin_amdgcn_mfma_f32_32x32x16_bf16(af0, wf0, a0, 0, 0, 0);  \
        a1 = __builtin_amdgcn_mfma_f32_32x32x16_bf16(af0, wf1, a1, 0, 0, 0);  \
    }                                                                         \
}

#define M2_EPI(ac, nn) {                                                      \
    float bl = (nn) ? blB : blA;                                              \
    int row_ = (nn) ? rowB : rowA;                                            \
    _Pragma("unroll")                                                         \
    for (int r = 0; r < 16; r++) {                                            \
        int m = (r & 3) + 8 * (r >> 2) + 4 * kh;                              \
        int tokg = c0 + wt * 32 + m;                                          \
        if (tokg < cnt) {                                                     \
            float y = ac[r] + bl;                                             \
            yb[(size_t)(sbase + tokg) * HD + row_] = (ushort)f2bf(y);         \
        }                                                                     \
    }                                                                         \
}

__global__ __launch_bounds__(256, 3) void k_mlp2(
    const ushort* __restrict__ a_k, const unsigned* __restrict__ wp,
    const ushort* __restrict__ sct, const float* __restrict__ bias,
    const int* __restrict__ counts, ushort* __restrict__ yb)
{
    int e = blockIdx.y;
    int cnt = counts[e];
    if (cnt == 0) return;
    int c00 = blockIdx.z * 64;
    if (c00 >= cnt) return;
    int r0 = blockIdx.x * 128;
    int tid = threadIdx.x;
    int l = tid & 63, lr = l & 31, kh = l >> 5;
    int wu = __builtin_amdgcn_readfirstlane(tid >> 6);
    int wr = wu >> 1, wt = wu & 1;
    int sbase = e << 10;

    __shared__ char lds_all[49152];
    char* myt = lds_all + wu * 12288;            // tokens: 2 x 4 KB
    char* myw = myt + 8192;                      // weights: 2 x 2 KB

    int rowA = r0 + wr * 64 + lr, rowB = rowA + 32;
    float blA = bias[e * HD + rowA];
    float blB = bias[e * HD + rowB];
    const uint4* spA = (const uint4*)(sct + (size_t)(e * HD + rowA) * 16);
    const uint4* spB = (const uint4*)(sct + (size_t)(e * HD + rowB) * 16);
    uint4 sA0 = spA[0], sA1 = spA[1];
    uint4 sB0 = spB[0], sB1 = spB[1];
    unsigned pin = sA0.x ^ sA0.y ^ sA0.z ^ sA0.w ^ sA1.x ^ sA1.y ^ sA1.z ^ sA1.w
                 ^ sB0.x ^ sB0.y ^ sB0.z ^ sB0.w ^ sB1.x ^ sB1.y ^ sB1.z ^ sB1.w;
    asm volatile("" :: "v"(pin), "v"(blA), "v"(blB));

    const char* wsrc = (const char*)wp + (size_t)e * 16 * 32768
                       + (size_t)(r0 + wr * 64) * 32 + (l >> 1) * 32 + (l & 1) * 16;
    int tswz = ((l & 7) ^ (l >> 3)) << 4;
    int swz0 = (lr ^ (lr >> 3)) & 7;
    int swz1 = swz0 ^ 4;

    #pragma unroll 1
    for (int c0 = c00; c0 < cnt; c0 += 192) {
        const char* tsrc = (const char*)a_k
            + (size_t)(sbase + c0 + wt * 32 + (l >> 3)) * 128 + tswz;
        asm volatile("s_waitcnt vmcnt(0)" ::: "memory"); SB;

        f32x16 a0 = {}, a1 = {};
        M2_ISSUE(0, 0); M2_ISSUE(1, 1); SB;

        #pragma unroll 1
        for (int kt2 = 0; kt2 < 16; kt2 += 2) {
            unsigned dwA = sc_sel(sA0, sA1, kt2);
            unsigned dwB = sc_sel(sB0, sB1, kt2);
            asm volatile("s_waitcnt vmcnt(6)" ::: "memory"); SB;
            M2_COMPUTE(0, dwA & 0xFFFFu, dwB & 0xFFFFu);
            asm volatile("s_waitcnt lgkmcnt(0)" ::: "memory"); SB;
            if (kt2 < 14) { M2_ISSUE(0, kt2 + 2); SB; }
            if (kt2 < 14) { asm volatile("s_waitcnt vmcnt(6)" ::: "memory"); }
            else          { asm volatile("s_waitcnt vmcnt(0)" ::: "memory"); }
            SB;
            M2_COMPUTE(1, dwA >> 16, dwB >> 16);
            asm volatile("s_waitcnt lgkmcnt(0)" ::: "memory"); SB;
            if (kt2 < 14) { M2_ISSUE(1, kt2 + 3); SB; }
        }

        M2_EPI(a0, 0); M2_EPI(a1, 1);
    }
}

__global__ __launch_bounds__(256) void k_combine(
    const float* __restrict__ x, const ushort* __restrict__ yb,
    const int* __restrict__ top_idx, const float* __restrict__ top_wt,
    const int* __restrict__ pos_of, float* __restrict__ out)
{
    int n = blockIdx.x, tid = threadIdx.x;
    float4 xv = ((const float4*)(x + (size_t)n * HD))[tid];
    float r0 = xv.x, r1 = xv.y, r2 = xv.z, r3 = xv.w;
    #pragma unroll
    for (int k = 0; k < 4; k++) {
        int e = top_idx[n * 4 + k];
        float wt = top_wt[n * 4 + k];
        int slot = (e << 10) + pos_of[n * 4 + k];
        ushort4 yv = ((const ushort4*)(yb + (size_t)slot * HD))[tid];
        r0 += wt * bf2f(yv.x); r1 += wt * bf2f(yv.y);
        r2 += wt * bf2f(yv.z); r3 += wt * bf2f(yv.w);
    }
    float4 ov; ov.x = r0; ov.y = r1; ov.z = r2; ov.w = r3;
    ((float4*)(out + (size_t)n * HD))[tid] = ov;
}

extern "C" void kernel_launch(void* const* d_in, const int* in_sizes, int n_in,
                              void* d_out, int out_size, void* d_ws, size_t ws_size,
                              hipStream_t stream)
{
    const float* x           = (const float*)d_in[0];
    const float* norm_w      = (const float*)d_in[1];
    const float* gate_w      = (const float*)d_in[2];
    const float* gate_b      = (const float*)d_in[3];
    const float* mlp1_bias   = (const float*)d_in[4];
    const float* mlp2_bias   = (const float*)d_in[5];
    const int*   mlp1_blocks = (const int*)d_in[6];
    const int*   mlp1_scales = (const int*)d_in[7];
    const int*   mlp2_blocks = (const int*)d_in[8];
    const int*   mlp2_scales = (const int*)d_in[9];
    float* out = (float*)d_out;

    char* ws = (char*)d_ws;
    unsigned* wp1  = (unsigned*)(ws + WP1_OFF);
    unsigned* wp2  = (unsigned*)(ws + WP2_OFF);
    ushort* sct1   = (ushort*)(ws + SCT1_OFF);
    ushort* sct2   = (ushort*)(ws + SCT2_OFF);
    ushort* t_s    = (ushort*)(ws + TS_OFF);
    ushort* a_k    = (ushort*)(ws + AK_OFF);
    ushort* yb     = (ushort*)(ws + YB_OFF);
    int*   counts  = (int*)(ws + CNT_OFF);
    int*   top_idx = (int*)(ws + TIDX_OFF);
    float* top_wt  = (float*)(ws + TWT_OFF);
    int*   pos_of  = (int*)(ws + POS_OFF);

    hipMemsetAsync(counts, 0, NE * sizeof(int), stream);
    k_repack<<<6528, 256, 0, stream>>>(mlp1_blocks, mlp2_blocks, mlp1_scales, mlp2_scales,
                                       wp1, wp2, sct1, sct2);
    k_gate<<<NTOK, 256, 0, stream>>>(x, norm_w, gate_w, gate_b, t_s, top_idx, top_wt,
                                     counts, pos_of);
    k_mlp1<<<dim3(16, NE, 2), 256, 0, stream>>>(t_s, wp1, sct1, mlp1_bias, counts, a_k);
    k_mlp2<<<dim3(8, NE, 3), 256, 0, stream>>>(a_k, wp2, sct2, mlp2_bias, counts, yb);
    k_combine<<<NTOK, 256, 0, stream>>>(x, yb, top_idx, top_wt, pos_of, out);
}